// Round 4
// baseline (553.974 us; speedup 1.0000x reference)
//
#include <hip/hip_runtime.h>

#define T_ 1024
#define H_ 32
#define P_ 64
#define N_ 128
#define L_ 64

typedef float f32x4 __attribute__((ext_vector_type(4)));
typedef short short8 __attribute__((ext_vector_type(8)));
typedef short short4v __attribute__((ext_vector_type(4)));

static __device__ __forceinline__ unsigned short f2bf(float f) {
  unsigned int u = __float_as_uint(f);
  u += 0x7fffu + ((u >> 16) & 1u);
  return (unsigned short)(u >> 16);
}
static __device__ __forceinline__ float bf2f(short s) {
  return __uint_as_float(((unsigned int)(unsigned short)s) << 16);
}

// ---------------------------------------------------------------------------
// Kernel 1: inclusive cumsum of A over t, per (b,h).
// ---------------------------------------------------------------------------
__global__ __launch_bounds__(1024) void cuma_kernel(const float* __restrict__ A,
                                                    float* __restrict__ cumA) {
  const int bh = blockIdx.x;
  const int b = bh >> 5, h = bh & 31;
  const int t = threadIdx.x;
  __shared__ float s[1024];
  s[t] = A[(b * T_ + t) * H_ + h];
  __syncthreads();
  for (int off = 1; off < 1024; off <<= 1) {
    float v = (t >= off) ? s[t - off] : 0.0f;
    __syncthreads();
    s[t] += v;
    __syncthreads();
  }
  cumA[bh * T_ + t] = s[t];
}

// ---------------------------------------------------------------------------
// prep: one launch. Per (bh, tb) 64-t tile:
//   B fp32 (b,t,h,n) -> Bbf [bh][t][n] bf16  AND  BT [bh][n][t] bf16
//   C fp32 (b,t,h,n) -> Cbf [bh][t][n] bf16
//   x fp32 (b,t,h,p) -> xT  [bh][p][t] bf16
// ---------------------------------------------------------------------------
__global__ __launch_bounds__(256) void prep_kernel(
    const float* __restrict__ x, const float* __restrict__ Bm,
    const float* __restrict__ Cm, short* __restrict__ Bbf,
    short* __restrict__ BT, short* __restrict__ Cbf,
    short* __restrict__ xT) {
  const int bh = blockIdx.x;   // 64
  const int tb = blockIdx.y;   // 16
  const int b = bh >> 5, h = bh & 31;
  const int tid = threadIdx.x;
  __shared__ short Bt[128][72];
  __shared__ short Xt[64][72];

  // B: convert + stage transpose
#pragma unroll
  for (int i = 0; i < 8; ++i) {
    const int idx = tid + 256 * i;  // 2048 float4 chunks (64 t x 32 n4)
    const int row = idx >> 5, n4 = idx & 31;
    const float4 v = *(const float4*)(Bm + ((size_t)(b * T_ + tb * 64 + row) * H_ + h) * N_ + n4 * 4);
    short4v o;
    o.x = (short)f2bf(v.x); o.y = (short)f2bf(v.y);
    o.z = (short)f2bf(v.z); o.w = (short)f2bf(v.w);
    *(short4v*)(Bbf + ((size_t)bh * T_ + tb * 64 + row) * N_ + n4 * 4) = o;
    Bt[n4 * 4 + 0][row] = o.x; Bt[n4 * 4 + 1][row] = o.y;
    Bt[n4 * 4 + 2][row] = o.z; Bt[n4 * 4 + 3][row] = o.w;
  }
  // C: convert only
#pragma unroll
  for (int i = 0; i < 8; ++i) {
    const int idx = tid + 256 * i;
    const int row = idx >> 5, n4 = idx & 31;
    const float4 v = *(const float4*)(Cm + ((size_t)(b * T_ + tb * 64 + row) * H_ + h) * N_ + n4 * 4);
    short4v o;
    o.x = (short)f2bf(v.x); o.y = (short)f2bf(v.y);
    o.z = (short)f2bf(v.z); o.w = (short)f2bf(v.w);
    *(short4v*)(Cbf + ((size_t)bh * T_ + tb * 64 + row) * N_ + n4 * 4) = o;
  }
  // x: stage transpose
#pragma unroll
  for (int i = 0; i < 4; ++i) {
    const int idx = tid + 256 * i;  // 1024 float4 chunks (64 t x 16 p4)
    const int row = idx >> 4, p4 = idx & 15;
    const float4 v = *(const float4*)(x + ((size_t)(b * T_ + tb * 64 + row) * H_ + h) * P_ + p4 * 4);
    Xt[p4 * 4 + 0][row] = (short)f2bf(v.x);
    Xt[p4 * 4 + 1][row] = (short)f2bf(v.y);
    Xt[p4 * 4 + 2][row] = (short)f2bf(v.z);
    Xt[p4 * 4 + 3][row] = (short)f2bf(v.w);
  }
  __syncthreads();
#pragma unroll
  for (int i = 0; i < 4; ++i) {
    const int idx = tid + 256 * i;  // 1024 short8 chunks (128 n x 8 t8)
    const int n = idx >> 3, t8 = idx & 7;
    const short4v a = *(const short4v*)&Bt[n][t8 * 8];
    const short4v c = *(const short4v*)&Bt[n][t8 * 8 + 4];
    short8 o;
    o[0] = a.x; o[1] = a.y; o[2] = a.z; o[3] = a.w;
    o[4] = c.x; o[5] = c.y; o[6] = c.z; o[7] = c.w;
    *(short8*)(BT + ((size_t)bh * N_ + n) * T_ + tb * 64 + t8 * 8) = o;
  }
#pragma unroll
  for (int i = 0; i < 2; ++i) {
    const int idx = tid + 256 * i;  // 512 short8 chunks (64 p x 8 t8)
    const int p = idx >> 3, t8 = idx & 7;
    const short4v a = *(const short4v*)&Xt[p][t8 * 8];
    const short4v c = *(const short4v*)&Xt[p][t8 * 8 + 4];
    short8 o;
    o[0] = a.x; o[1] = a.y; o[2] = a.z; o[3] = a.w;
    o[4] = c.x; o[5] = c.y; o[6] = c.z; o[7] = c.w;
    *(short8*)(xT + ((size_t)bh * P_ + p) * T_ + tb * 64 + t8 * 8) = o;
  }
}

// ---------------------------------------------------------------------------
// attn: barrier-free, wave-independent, with software prefetch of the
// cold-HBM mask stream (kc+1 issued at top of kc's iteration).
// ---------------------------------------------------------------------------
__global__ __launch_bounds__(256, 4) void attn_kernel(
    const short* __restrict__ xT, const short* __restrict__ Bbf,
    const short* __restrict__ Cbf, const float* __restrict__ mask,
    const float* __restrict__ msf_p, const float* __restrict__ cumA,
    float* __restrict__ Y) {
  const int blk = blockIdx.x;       // 1024
  const int qc = 15 - (blk >> 6);   // heavy jobs dispatch first
  const int bh = blk & 63;
  const int b = bh >> 5, h = bh & 31;
  const float msf = msf_p[0];
  const int tid = threadIdx.x;
  const int w = tid >> 6;
  const int lane = tid & 63;
  const int q = lane >> 4, c = lane & 15;

  __shared__ short Ps[4][16][72];   // wave-private C/D->A layout round-trip

  // ---- C fragments (bf16, 4 x b128) + query cumA ----
  short8 cf[4];
  {
    const short* Cg = Cbf + ((size_t)bh * T_ + qc * L_ + 16 * w + c) * N_ + 8 * q;
#pragma unroll
    for (int kt = 0; kt < 4; ++kt) cf[kt] = *(const short8*)(Cg + kt * 32);
  }
  float ca_i[4];
#pragma unroll
  for (int r = 0; r < 4; ++r)
    ca_i[r] = cumA[bh * T_ + qc * L_ + 16 * w + 4 * q + r];

  f32x4 yacc[4];
#pragma unroll
  for (int pt = 0; pt < 4; ++pt) yacc[pt] = (f32x4){0.f, 0.f, 0.f, 0.f};

  const float* mrow0 = mask + ((size_t)bh * T_ + (size_t)(qc * L_ + 16 * w + 4 * q)) * T_ + c;

  // ---- prologue: prefetch mask + key cumA for kc=0 ----
  float mv[16], ck[4];
  {
    const float* mb = mrow0;
#pragma unroll
    for (int tj = 0; tj < 4; ++tj)
#pragma unroll
      for (int r = 0; r < 4; ++r)
        mv[tj * 4 + r] = __builtin_nontemporal_load(mb + (size_t)r * T_ + 16 * tj);
#pragma unroll
    for (int tj = 0; tj < 4; ++tj) ck[tj] = cumA[bh * T_ + 16 * tj + c];
  }

  for (int kc = 0; kc <= qc; ++kc) {
    // ---- prefetch next tile's mask + cumA (consumed next iteration) ----
    float mvn[16], ckn[4];
    if (kc < qc) {
      const float* mb = mrow0 + (size_t)(kc + 1) * L_;
#pragma unroll
      for (int tj = 0; tj < 4; ++tj)
#pragma unroll
        for (int r = 0; r < 4; ++r)
          mvn[tj * 4 + r] = __builtin_nontemporal_load(mb + (size_t)r * T_ + 16 * tj);
#pragma unroll
      for (int tj = 0; tj < 4; ++tj)
        ckn[tj] = cumA[bh * T_ + (kc + 1) * L_ + 16 * tj + c];
    }

    // ---- S = C . B^T (bf16 frags from global; L2-warm) ----
    f32x4 sacc[4];
#pragma unroll
    for (int tj = 0; tj < 4; ++tj) sacc[tj] = (f32x4){0.f, 0.f, 0.f, 0.f};
    const short* Bg = Bbf + ((size_t)bh * T_ + kc * L_) * N_ + 8 * q;
#pragma unroll
    for (int kt = 0; kt < 4; ++kt) {
#pragma unroll
      for (int tj = 0; tj < 4; ++tj) {
        const short8 bf = *(const short8*)(Bg + (size_t)(16 * tj + c) * N_ + kt * 32);
        sacc[tj] = __builtin_amdgcn_mfma_f32_16x16x32_bf16(cf[kt], bf, sacc[tj], 0, 0, 0);
      }
    }

    // ---- weight -> Ps (wave-private; no barrier) ----
    const bool diag = (kc == qc);
#pragma unroll
    for (int tj = 0; tj < 4; ++tj) {
      const int j_l = 16 * tj + c;
#pragma unroll
      for (int r = 0; r < 4; ++r) {
        const int i_l = 16 * w + 4 * q + r;
        float wgt = __expf(ca_i[r] - ck[tj]) + msf * mv[tj * 4 + r];
        if (diag && j_l > i_l) wgt = 0.0f;
        Ps[w][4 * q + r][j_l] = (short)f2bf(sacc[tj][r] * wgt);
      }
    }

    // ---- Y += P . x ----
#pragma unroll
    for (int kt2 = 0; kt2 < 2; ++kt2) {
      const short8 pf = *(const short8*)&Ps[w][c][kt2 * 32 + 8 * q];
      const short* xg = xT + (size_t)bh * P_ * T_ + kc * L_ + kt2 * 32 + 8 * q;
#pragma unroll
      for (int pt = 0; pt < 4; ++pt) {
        const short8 xf = *(const short8*)(xg + (size_t)(16 * pt + c) * T_);
        yacc[pt] = __builtin_amdgcn_mfma_f32_16x16x32_bf16(pf, xf, yacc[pt], 0, 0, 0);
      }
    }

    // ---- rotate prefetched values ----
#pragma unroll
    for (int e = 0; e < 16; ++e) mv[e] = mvn[e];
#pragma unroll
    for (int e = 0; e < 4; ++e) ck[e] = ckn[e];
  }

  // ---- write Y (nontemporal; write-once) ----
  float* Yg = Y + ((size_t)(b * T_ + qc * L_ + 16 * w + 4 * q) * H_ + h) * P_;
#pragma unroll
  for (int pt = 0; pt < 4; ++pt)
#pragma unroll
    for (int r = 0; r < 4; ++r)
      __builtin_nontemporal_store(yacc[pt][r], Yg + (size_t)r * (H_ * P_) + 16 * pt + c);
}

// ---------------------------------------------------------------------------
// state: final_state[p][n] = sum_t (w_t*x[t,p]) * B[t,n]; MFMA over xT/BT.
// ---------------------------------------------------------------------------
__global__ __launch_bounds__(512) void state_kernel(
    const short* __restrict__ xT, const short* __restrict__ BT,
    const float* __restrict__ cumA, float* __restrict__ out) {
  const int bh = blockIdx.x;
  const int tid = threadIdx.x;
  const int w = (tid >> 6) & 3;   // p strip
  const int th = tid >> 8;        // t half
  const int lane = tid & 63;
  const int q = lane >> 4, c = lane & 15;

  __shared__ float wsh[1024];
  __shared__ float red[4][16][128];
  {
    const float cend = cumA[bh * T_ + (T_ - 1)];
    for (int t = tid; t < 1024; t += 512)
      wsh[t] = __expf(cend - cumA[bh * T_ + t]);
  }
  __syncthreads();

  f32x4 acc[8];
#pragma unroll
  for (int nt = 0; nt < 8; ++nt) acc[nt] = (f32x4){0.f, 0.f, 0.f, 0.f};

  for (int ktl = 0; ktl < 16; ++ktl) {
    const int t0 = th * 512 + ktl * 32;
    const short8 xv = *(const short8*)(xT + ((size_t)bh * P_ + 16 * w + c) * T_ + t0 + 8 * q);
    const float4 w0 = *(const float4*)&wsh[t0 + 8 * q];
    const float4 w1 = *(const float4*)&wsh[t0 + 8 * q + 4];
    short8 af;
    af[0] = (short)f2bf(bf2f(xv[0]) * w0.x); af[1] = (short)f2bf(bf2f(xv[1]) * w0.y);
    af[2] = (short)f2bf(bf2f(xv[2]) * w0.z); af[3] = (short)f2bf(bf2f(xv[3]) * w0.w);
    af[4] = (short)f2bf(bf2f(xv[4]) * w1.x); af[5] = (short)f2bf(bf2f(xv[5]) * w1.y);
    af[6] = (short)f2bf(bf2f(xv[6]) * w1.z); af[7] = (short)f2bf(bf2f(xv[7]) * w1.w);
#pragma unroll
    for (int nt = 0; nt < 8; ++nt) {
      const short8 bf = *(const short8*)(BT + ((size_t)bh * N_ + 16 * nt + c) * T_ + t0 + 8 * q);
      acc[nt] = __builtin_amdgcn_mfma_f32_16x16x32_bf16(af, bf, acc[nt], 0, 0, 0);
    }
  }

  if (th == 1) {
#pragma unroll
    for (int nt = 0; nt < 8; ++nt)
#pragma unroll
      for (int r = 0; r < 4; ++r) red[w][4 * q + r][16 * nt + c] = acc[nt][r];
  }
  __syncthreads();
  if (th == 0) {
    float* o = out + (size_t)bh * P_ * N_;
#pragma unroll
    for (int nt = 0; nt < 8; ++nt)
#pragma unroll
      for (int r = 0; r < 4; ++r)
        o[(size_t)(16 * w + 4 * q + r) * N_ + 16 * nt + c] =
            acc[nt][r] + red[w][4 * q + r][16 * nt + c];
  }
}

// ---------------------------------------------------------------------------
extern "C" void kernel_launch(void* const* d_in, const int* in_sizes, int n_in,
                              void* d_out, int out_size, void* d_ws, size_t ws_size,
                              hipStream_t stream) {
  const float* x    = (const float*)d_in[0];
  const float* A    = (const float*)d_in[1];
  const float* Bm   = (const float*)d_in[2];
  const float* Cm   = (const float*)d_in[3];
  const float* mask = (const float*)d_in[4];
  const float* msf  = (const float*)d_in[5];
  float* Y  = (float*)d_out;
  float* fs = (float*)d_out + (size_t)2 * T_ * H_ * P_;

  char* ws = (char*)d_ws;
  float* cumA = (float*)ws;                                   // 256 KB
  size_t off = 1 << 18;
  short* Bbf = (short*)(ws + off); off += (size_t)64 * T_ * N_ * 2;   // 16 MB
  short* BT  = (short*)(ws + off); off += (size_t)64 * T_ * N_ * 2;   // 16 MB
  short* Cbf = (short*)(ws + off); off += (size_t)64 * T_ * N_ * 2;   // 16 MB
  short* xT  = (short*)(ws + off);                                    // 8 MB

  cuma_kernel<<<64, 1024, 0, stream>>>(A, cumA);
  prep_kernel<<<dim3(64, 16), 256, 0, stream>>>(x, Bm, Cm, Bbf, BT, Cbf, xT);
  attn_kernel<<<1024, 256, 0, stream>>>(xT, Bbf, Cbf, mask, msf, cumA, Y);
  state_kernel<<<64, 512, 0, stream>>>(xT, BT, cumA, fs);
}

// Round 5
// 505.113 us; speedup vs baseline: 1.0967x; 1.0967x over previous
//
#include <hip/hip_runtime.h>

#define T_ 1024
#define H_ 32
#define P_ 64
#define N_ 128
#define L_ 64

typedef float f32x4 __attribute__((ext_vector_type(4)));
typedef short short8 __attribute__((ext_vector_type(8)));
typedef short short4v __attribute__((ext_vector_type(4)));

static __device__ __forceinline__ unsigned short f2bf(float f) {
  unsigned int u = __float_as_uint(f);
  u += 0x7fffu + ((u >> 16) & 1u);
  return (unsigned short)(u >> 16);
}
static __device__ __forceinline__ float bf2f(short s) {
  return __uint_as_float(((unsigned int)(unsigned short)s) << 16);
}

// ---------------------------------------------------------------------------
// Kernel 1: inclusive cumsum of A over t, per (b,h).
// ---------------------------------------------------------------------------
__global__ __launch_bounds__(1024) void cuma_kernel(const float* __restrict__ A,
                                                    float* __restrict__ cumA) {
  const int bh = blockIdx.x;
  const int b = bh >> 5, h = bh & 31;
  const int t = threadIdx.x;
  __shared__ float s[1024];
  s[t] = A[(b * T_ + t) * H_ + h];
  __syncthreads();
  for (int off = 1; off < 1024; off <<= 1) {
    float v = (t >= off) ? s[t - off] : 0.0f;
    __syncthreads();
    s[t] += v;
    __syncthreads();
  }
  cumA[bh * T_ + t] = s[t];
}

// ---------------------------------------------------------------------------
// prep: B -> Bbf [bh][t][n] + BT [bh][n][t]; C -> Cbf [bh][t][n]; x -> xT [bh][p][t]
// ---------------------------------------------------------------------------
__global__ __launch_bounds__(256) void prep_kernel(
    const float* __restrict__ x, const float* __restrict__ Bm,
    const float* __restrict__ Cm, short* __restrict__ Bbf,
    short* __restrict__ BT, short* __restrict__ Cbf,
    short* __restrict__ xT) {
  const int bh = blockIdx.x;   // 64
  const int tb = blockIdx.y;   // 16
  const int b = bh >> 5, h = bh & 31;
  const int tid = threadIdx.x;
  __shared__ short Bt[128][72];
  __shared__ short Xt[64][72];

#pragma unroll
  for (int i = 0; i < 8; ++i) {
    const int idx = tid + 256 * i;
    const int row = idx >> 5, n4 = idx & 31;
    const float4 v = *(const float4*)(Bm + ((size_t)(b * T_ + tb * 64 + row) * H_ + h) * N_ + n4 * 4);
    short4v o;
    o.x = (short)f2bf(v.x); o.y = (short)f2bf(v.y);
    o.z = (short)f2bf(v.z); o.w = (short)f2bf(v.w);
    *(short4v*)(Bbf + ((size_t)bh * T_ + tb * 64 + row) * N_ + n4 * 4) = o;
    Bt[n4 * 4 + 0][row] = o.x; Bt[n4 * 4 + 1][row] = o.y;
    Bt[n4 * 4 + 2][row] = o.z; Bt[n4 * 4 + 3][row] = o.w;
  }
#pragma unroll
  for (int i = 0; i < 8; ++i) {
    const int idx = tid + 256 * i;
    const int row = idx >> 5, n4 = idx & 31;
    const float4 v = *(const float4*)(Cm + ((size_t)(b * T_ + tb * 64 + row) * H_ + h) * N_ + n4 * 4);
    short4v o;
    o.x = (short)f2bf(v.x); o.y = (short)f2bf(v.y);
    o.z = (short)f2bf(v.z); o.w = (short)f2bf(v.w);
    *(short4v*)(Cbf + ((size_t)bh * T_ + tb * 64 + row) * N_ + n4 * 4) = o;
  }
#pragma unroll
  for (int i = 0; i < 4; ++i) {
    const int idx = tid + 256 * i;
    const int row = idx >> 4, p4 = idx & 15;
    const float4 v = *(const float4*)(x + ((size_t)(b * T_ + tb * 64 + row) * H_ + h) * P_ + p4 * 4);
    Xt[p4 * 4 + 0][row] = (short)f2bf(v.x);
    Xt[p4 * 4 + 1][row] = (short)f2bf(v.y);
    Xt[p4 * 4 + 2][row] = (short)f2bf(v.z);
    Xt[p4 * 4 + 3][row] = (short)f2bf(v.w);
  }
  __syncthreads();
#pragma unroll
  for (int i = 0; i < 4; ++i) {
    const int idx = tid + 256 * i;
    const int n = idx >> 3, t8 = idx & 7;
    const short4v a = *(const short4v*)&Bt[n][t8 * 8];
    const short4v c = *(const short4v*)&Bt[n][t8 * 8 + 4];
    short8 o;
    o[0] = a.x; o[1] = a.y; o[2] = a.z; o[3] = a.w;
    o[4] = c.x; o[5] = c.y; o[6] = c.z; o[7] = c.w;
    *(short8*)(BT + ((size_t)bh * N_ + n) * T_ + tb * 64 + t8 * 8) = o;
  }
#pragma unroll
  for (int i = 0; i < 2; ++i) {
    const int idx = tid + 256 * i;
    const int p = idx >> 3, t8 = idx & 7;
    const short4v a = *(const short4v*)&Xt[p][t8 * 8];
    const short4v c = *(const short4v*)&Xt[p][t8 * 8 + 4];
    short8 o;
    o[0] = a.x; o[1] = a.y; o[2] = a.z; o[3] = a.w;
    o[4] = c.x; o[5] = c.y; o[6] = c.z; o[7] = c.w;
    *(short8*)(xT + ((size_t)bh * P_ + p) * T_ + tb * 64 + t8 * 8) = o;
  }
}

// ---------------------------------------------------------------------------
// attn: barrier-free, wave-independent. Issue order == consumption order:
// B(kc) -> x(kc) -> mask(kc+1). mask double-buffered via manually alternated
// macro (no rotation, no in-loop branch -> no scratch spill).
// ---------------------------------------------------------------------------
__global__ __launch_bounds__(256, 2) void attn_kernel(
    const short* __restrict__ xT, const short* __restrict__ Bbf,
    const short* __restrict__ Cbf, const float* __restrict__ mask,
    const float* __restrict__ msf_p, const float* __restrict__ cumA,
    float* __restrict__ Y) {
  const int blk = blockIdx.x;       // 1024
  const int qc = 15 - (blk >> 6);   // heavy jobs dispatch first
  const int bh = blk & 63;
  const int b = bh >> 5, h = bh & 31;
  const float msf = msf_p[0];
  const int tid = threadIdx.x;
  const int w = tid >> 6;
  const int lane = tid & 63;
  const int q = lane >> 4, c = lane & 15;

  __shared__ short Ps[4][16][72];

  short8 cf[4];
  {
    const short* Cg = Cbf + ((size_t)bh * T_ + qc * L_ + 16 * w + c) * N_ + 8 * q;
#pragma unroll
    for (int kt = 0; kt < 4; ++kt) cf[kt] = *(const short8*)(Cg + kt * 32);
  }
  float ca_i[4];
#pragma unroll
  for (int r = 0; r < 4; ++r)
    ca_i[r] = cumA[bh * T_ + qc * L_ + 16 * w + 4 * q + r];

  f32x4 yacc[4];
#pragma unroll
  for (int pt = 0; pt < 4; ++pt) yacc[pt] = (f32x4){0.f, 0.f, 0.f, 0.f};

  const float* mrow0 = mask + ((size_t)bh * T_ + (size_t)(qc * L_ + 16 * w + 4 * q)) * T_ + c;
  const short* Bg0 = Bbf + (size_t)bh * T_ * N_ + 8 * q;
  const short* xg0 = xT + (size_t)bh * P_ * T_ + 8 * q;

  float mvA[16], mvB[16], ckA[4], ckB[4];
  // prologue: mask/ck for kc=0 into buffer A
#pragma unroll
  for (int tj = 0; tj < 4; ++tj)
#pragma unroll
    for (int r = 0; r < 4; ++r)
      mvA[tj * 4 + r] = __builtin_nontemporal_load(mrow0 + (size_t)r * T_ + 16 * tj);
#pragma unroll
  for (int tj = 0; tj < 4; ++tj) ckA[tj] = cumA[bh * T_ + 16 * tj + c];

// One pipeline stage. Consumes MVI/CKI for tile KC; prefetches mask/ck for
// KC+1 (clamped) into MVO/CKO. VMEM issue order: B, x, mask/ck.
#define ATTN_STEP(KC, MVI, CKI, MVO, CKO)                                      \
  {                                                                            \
    const int kc_ = (KC);                                                      \
    const int kcn_ = (kc_ + 1 <= qc) ? (kc_ + 1) : qc;                         \
    short8 bfr[16];                                                            \
    const short* Bg = Bg0 + (size_t)kc_ * L_ * N_;                             \
    _Pragma("unroll") for (int kt = 0; kt < 4; ++kt)                           \
        _Pragma("unroll") for (int tj = 0; tj < 4; ++tj)                       \
            bfr[kt * 4 + tj] =                                                 \
        *(const short8*)(Bg + (size_t)(16 * tj + c) * N_ + kt * 32);           \
    short8 xfr[8];                                                             \
    const short* xg = xg0 + kc_ * L_;                                          \
    _Pragma("unroll") for (int kt2 = 0; kt2 < 2; ++kt2)                        \
        _Pragma("unroll") for (int pt = 0; pt < 4; ++pt)                       \
            xfr[kt2 * 4 + pt] =                                                \
        *(const short8*)(xg + (size_t)(16 * pt + c) * T_ + kt2 * 32);          \
    const float* mb = mrow0 + (size_t)kcn_ * L_;                               \
    _Pragma("unroll") for (int tj = 0; tj < 4; ++tj)                           \
        _Pragma("unroll") for (int r = 0; r < 4; ++r)                          \
            MVO[tj * 4 + r] =                                                  \
        __builtin_nontemporal_load(mb + (size_t)r * T_ + 16 * tj);             \
    _Pragma("unroll") for (int tj = 0; tj < 4; ++tj)                           \
        CKO[tj] = cumA[bh * T_ + kcn_ * L_ + 16 * tj + c];                     \
    f32x4 sacc[4];                                                             \
    _Pragma("unroll") for (int tj = 0; tj < 4; ++tj)                           \
        sacc[tj] = (f32x4){0.f, 0.f, 0.f, 0.f};                                \
    _Pragma("unroll") for (int kt = 0; kt < 4; ++kt)                           \
        _Pragma("unroll") for (int tj = 0; tj < 4; ++tj)                       \
            sacc[tj] = __builtin_amdgcn_mfma_f32_16x16x32_bf16(                \
        cf[kt], bfr[kt * 4 + tj], sacc[tj], 0, 0, 0);                          \
    const bool diag = (kc_ == qc);                                             \
    _Pragma("unroll") for (int tj = 0; tj < 4; ++tj) {                         \
      const int j_l = 16 * tj + c;                                             \
      _Pragma("unroll") for (int r = 0; r < 4; ++r) {                          \
        const int i_l = 16 * w + 4 * q + r;                                    \
        float wgt = __expf(ca_i[r] - CKI[tj]) + msf * MVI[tj * 4 + r];         \
        if (diag && j_l > i_l) wgt = 0.0f;                                     \
        Ps[w][4 * q + r][j_l] = (short)f2bf(sacc[tj][r] * wgt);                \
      }                                                                        \
    }                                                                          \
    _Pragma("unroll") for (int kt2 = 0; kt2 < 2; ++kt2) {                      \
      const short8 pf = *(const short8*)&Ps[w][c][kt2 * 32 + 8 * q];           \
      _Pragma("unroll") for (int pt = 0; pt < 4; ++pt)                         \
          yacc[pt] = __builtin_amdgcn_mfma_f32_16x16x32_bf16(                  \
          pf, xfr[kt2 * 4 + pt], yacc[pt], 0, 0, 0);                           \
    }                                                                          \
  }

  int kc = 0;
  for (; kc + 1 <= qc; kc += 2) {
    ATTN_STEP(kc, mvA, ckA, mvB, ckB)
    ATTN_STEP(kc + 1, mvB, ckB, mvA, ckA)
  }
  if (kc <= qc) {
    ATTN_STEP(kc, mvA, ckA, mvB, ckB)
  }
#undef ATTN_STEP

  float* Yg = Y + ((size_t)(b * T_ + qc * L_ + 16 * w + 4 * q) * H_ + h) * P_;
#pragma unroll
  for (int pt = 0; pt < 4; ++pt)
#pragma unroll
    for (int r = 0; r < 4; ++r)
      __builtin_nontemporal_store(yacc[pt][r], Yg + (size_t)r * (H_ * P_) + 16 * pt + c);
}

// ---------------------------------------------------------------------------
// zero_fs: final_state accumulator init (d_out is poisoned each launch).
// ---------------------------------------------------------------------------
__global__ __launch_bounds__(256) void zero_fs(float* __restrict__ fs) {
  const int i = blockIdx.x * 256 + threadIdx.x;
  ((float4*)fs)[i] = make_float4(0.f, 0.f, 0.f, 0.f);
}

// ---------------------------------------------------------------------------
// state: final_state[p][n] = sum_t (w_t*x[t,p]) * B[t,n]; MFMA over xT/BT,
// t split 4 ways across blocks, fp32 atomicAdd combine.
// ---------------------------------------------------------------------------
__global__ __launch_bounds__(256) void state_kernel(
    const short* __restrict__ xT, const short* __restrict__ BT,
    const float* __restrict__ cumA, float* __restrict__ out) {
  const int bh = blockIdx.x;   // 64
  const int tq = blockIdx.y;   // 4 t-quarters
  const int tid = threadIdx.x;
  const int w = tid >> 6;      // p strip
  const int lane = tid & 63;
  const int q = lane >> 4, c = lane & 15;

  __shared__ float wsh[256];
  {
    const float cend = cumA[bh * T_ + (T_ - 1)];
    wsh[tid] = __expf(cend - cumA[bh * T_ + tq * 256 + tid]);
  }
  __syncthreads();

  f32x4 acc[8];
#pragma unroll
  for (int nt = 0; nt < 8; ++nt) acc[nt] = (f32x4){0.f, 0.f, 0.f, 0.f};

#pragma unroll
  for (int ktl = 0; ktl < 8; ++ktl) {
    const int t0 = ktl * 32;
    const int tg = tq * 256 + t0;
    const short8 xv = *(const short8*)(xT + ((size_t)bh * P_ + 16 * w + c) * T_ + tg + 8 * q);
    const float4 w0 = *(const float4*)&wsh[t0 + 8 * q];
    const float4 w1 = *(const float4*)&wsh[t0 + 8 * q + 4];
    short8 af;
    af[0] = (short)f2bf(bf2f(xv[0]) * w0.x); af[1] = (short)f2bf(bf2f(xv[1]) * w0.y);
    af[2] = (short)f2bf(bf2f(xv[2]) * w0.z); af[3] = (short)f2bf(bf2f(xv[3]) * w0.w);
    af[4] = (short)f2bf(bf2f(xv[4]) * w1.x); af[5] = (short)f2bf(bf2f(xv[5]) * w1.y);
    af[6] = (short)f2bf(bf2f(xv[6]) * w1.z); af[7] = (short)f2bf(bf2f(xv[7]) * w1.w);
#pragma unroll
    for (int nt = 0; nt < 8; ++nt) {
      const short8 bf = *(const short8*)(BT + ((size_t)bh * N_ + 16 * nt + c) * T_ + tg + 8 * q);
      acc[nt] = __builtin_amdgcn_mfma_f32_16x16x32_bf16(af, bf, acc[nt], 0, 0, 0);
    }
  }

  float* o = out + (size_t)bh * P_ * N_;
#pragma unroll
  for (int nt = 0; nt < 8; ++nt)
#pragma unroll
    for (int r = 0; r < 4; ++r)
      atomicAdd(&o[(size_t)(16 * w + 4 * q + r) * N_ + 16 * nt + c], acc[nt][r]);
}

// ---------------------------------------------------------------------------
extern "C" void kernel_launch(void* const* d_in, const int* in_sizes, int n_in,
                              void* d_out, int out_size, void* d_ws, size_t ws_size,
                              hipStream_t stream) {
  const float* x    = (const float*)d_in[0];
  const float* A    = (const float*)d_in[1];
  const float* Bm   = (const float*)d_in[2];
  const float* Cm   = (const float*)d_in[3];
  const float* mask = (const float*)d_in[4];
  const float* msf  = (const float*)d_in[5];
  float* Y  = (float*)d_out;
  float* fs = (float*)d_out + (size_t)2 * T_ * H_ * P_;

  char* ws = (char*)d_ws;
  float* cumA = (float*)ws;
  size_t off = 1 << 18;
  short* Bbf = (short*)(ws + off); off += (size_t)64 * T_ * N_ * 2;
  short* BT  = (short*)(ws + off); off += (size_t)64 * T_ * N_ * 2;
  short* Cbf = (short*)(ws + off); off += (size_t)64 * T_ * N_ * 2;
  short* xT  = (short*)(ws + off);

  cuma_kernel<<<64, 1024, 0, stream>>>(A, cumA);
  prep_kernel<<<dim3(64, 16), 256, 0, stream>>>(x, Bm, Cm, Bbf, BT, Cbf, xT);
  attn_kernel<<<1024, 256, 0, stream>>>(xT, Bbf, Cbf, mask, msf, cumA, Y);
  zero_fs<<<512, 256, 0, stream>>>(fs);
  state_kernel<<<dim3(64, 4), 256, 0, stream>>>(xT, BT, cumA, fs);
}